// Round 11
// baseline (135.653 us; speedup 1.0000x reference)
//
#include <hip/hip_runtime.h>
#include <stdint.h>

// Problem constants
#define NNODES 50000
#define NEDGES 1000000
#define DIM    64
#define NREL   8
#define NBIN   489          // build blocks: 2048 edges each (489*2048 >= 1M)
#define NBINB  3125         // 16-node bins (dst>>4); 3125*16 == 50000 exactly
#define NBINBP 4096         // lhist/lscan pad to 1024*4 for the 4-elem scan
#define TPITCH 3136         // tab row pitch (ushorts), row-major by build block
#define BCAP   480          // per-bucket record cap (mean 320, sd ~18 -> +8.9 sigma)
#define BCAP2  736          // padded sorted[] capacity: 480 + 8 waves * 31 pad
#define PITCH  592          // At row pitch (shorts): 512 agg + 64 self + pad
#define PREPN  (18 * 4 * 64 * 8)

typedef __attribute__((ext_vector_type(8))) short short8;
typedef __attribute__((ext_vector_type(4))) float float4v;
typedef __attribute__((ext_vector_type(4))) unsigned short us4;
typedef long long i64;

__device__ __forceinline__ unsigned short f2bf(float f) {
  unsigned int u = __float_as_uint(f);
  unsigned int r = (u + 0x7FFF + ((u >> 16) & 1)) >> 16;   // round-nearest-even
  return (unsigned short)r;
}
// f32 -> fp8 e4m3 (RNE, tiny values flushed to sign-only; |x|<6 so no sat needed)
__device__ __forceinline__ unsigned int f2fp8(float f) {
  unsigned u = __float_as_uint(f);
  unsigned s = (u >> 24) & 0x80u;
  unsigned a = u & 0x7FFFFFFFu;
  if (a < 0x3C800000u) return s;                 // |x| < 2^-6
  unsigned r = a + 0x7FFFFu + ((a >> 20) & 1u);
  return s | (((r >> 20) - 960u) & 0x7Fu);
}
// pack 4 zero-extended bytes -> dword (byte n = fp8 element j=n)
__device__ __forceinline__ unsigned pk4(unsigned a, unsigned b, unsigned c, unsigned d) {
  return a | (b << 8) | (c << 16) | (d << 24);
}

// K0: build. 1024 threads/block, 2 edges/thread. Prologue: x f32 -> bf16 (xb)
// AND fp8 (xq) + B-prep + bias. Main: LDS counting sort by 16-node bin
// (dst>>4), flush to staged2[j*2048..].
// Record: x=(src<<6)|key<<23, key=(dst&15)*8+rel.
// ROUND-11 CHANGE: y = f2fp8(w) (fp8 byte, was f32 bits) -- the consumer's
// aggregation now runs on native fp8 MFMA, so w is pre-quantized here.
// (w=1.0 -> 0x38, exact in e4m3.) tab[j*TPITCH+bin] = off(11b)|cnt(5b)<<11.
__global__ __launch_bounds__(1024, 8) void build_kernel(
    const float4* __restrict__ x4,
    const float* __restrict__ Wlin, const float* __restrict__ Wself,
    const float* __restrict__ blin, const float* __restrict__ bself,
    const int2* __restrict__ src2, const int2* __restrict__ dst2,
    const int2* __restrict__ rel2, const float2* __restrict__ w2,
    us4* __restrict__ xb, unsigned int* __restrict__ xq4,
    unsigned short* __restrict__ Bf2, float* __restrict__ bsum,
    uint2* __restrict__ staged2, unsigned short* __restrict__ tab, int E2) {
  __shared__ int lhist[NBINBP];             // 16 KB
  __shared__ int lscan[NBINBP];             // 16 KB
  __shared__ uint2 lrec[2048];              // 16 KB
  __shared__ int wsumB[16];
  int tid = threadIdx.x;
  int lane = tid & 63;
  int wave = tid >> 6;                      // 0..15
  int j = blockIdx.x;
  int gid = j * 1024 + tid;
  const int TOT = NBIN * 1024;

  for (int t = gid; t < NNODES * DIM / 4; t += TOT) {
    float4 v = x4[t];
    us4 o;
    o.x = f2bf(v.x); o.y = f2bf(v.y); o.z = f2bf(v.z); o.w = f2bf(v.w);
    xb[t] = o;
    xq4[t] = f2fp8(v.x) | (f2fp8(v.y) << 8) | (f2fp8(v.z) << 16) | (f2fp8(v.w) << 24);
  }
  if (gid < PREPN) {
    int t = gid;
    int jj = t & 7;
    int l  = (t >> 3) & 63;
    int ct = (t >> 9) & 3;
    int ks = t >> 11;
    int k = ks * 32 + (l >> 4) * 8 + jj;
    int c = ct * 16 + (l & 15);
    float v = (k < 512) ? Wlin[(size_t)k * 64 + c] : Wself[(size_t)(k - 512) * 64 + c];
    Bf2[t] = f2bf(v);
  }
  if (gid < 64) bsum[gid] = blin[gid] + bself[gid];

  for (int i = tid; i < NBINBP; i += 1024) lhist[i] = 0;
  __syncthreads();
  bool valid = gid < E2;
  int2 s = {0,0}, d = {0,0}, r = {0,0};
  float2 w = {0.f,0.f};
  if (valid) { s = src2[gid]; d = dst2[gid]; r = rel2[gid]; w = w2[gid]; }
  int b0=0,b1=0,p0=0,p1=0;
  if (valid) {
    b0 = d.x >> 4; p0 = atomicAdd(&lhist[b0], 1);
    b1 = d.y >> 4; p1 = atomicAdd(&lhist[b1], 1);
  }
  __syncthreads();
  {                 // 16-wave exclusive scan of 4096 bin counts, 4 elems/thread
    int base4 = tid * 4;
    int l0 = lhist[base4 + 0], l1 = lhist[base4 + 1],
        l2 = lhist[base4 + 2], l3 = lhist[base4 + 3];
    int c1 = l0, c2 = c1 + l1, c3 = c2 + l2, s4 = c3 + l3;
    int inc = s4;
    #pragma unroll
    for (int dd = 1; dd < 64; dd <<= 1) {
      int tt = __shfl_up(inc, dd);
      if (lane >= dd) inc += tt;
    }
    if (lane == 63) wsumB[wave] = inc;
    __syncthreads();
    int off = 0;
    #pragma unroll
    for (int i = 0; i < 16; i++) { int pv = wsumB[i]; off += (i < wave) ? pv : 0; }
    int excl = off + inc - s4;
    lscan[base4 + 0] = excl;
    lscan[base4 + 1] = excl + c1;
    lscan[base4 + 2] = excl + c2;
    lscan[base4 + 3] = excl + c3;
  }
  __syncthreads();
  if (valid) {
    int q;
    unsigned k0 = (((unsigned)(d.x & 15) << 3) | (unsigned)r.x) << 23;
    unsigned k1 = (((unsigned)(d.y & 15) << 3) | (unsigned)r.y) << 23;
    q = lscan[b0] + p0; lrec[q] = make_uint2(((unsigned)s.x << 6) | k0, f2fp8(w.x));
    q = lscan[b1] + p1; lrec[q] = make_uint2(((unsigned)s.y << 6) | k1, f2fp8(w.y));
  }
  __syncthreads();
  for (int i = tid; i < NBINB; i += 1024) {    // COALESCED row-major run table
    int c = lhist[i];
    int cc = (c < 31) ? c : 31;
    unsigned short pk = (c > 0) ? (unsigned short)((unsigned)lscan[i] | ((unsigned)cc << 11)) : (unsigned short)0;
    tab[(size_t)j * TPITCH + i] = pk;
  }
  int cntblk = NEDGES - j * 2048;
  if (cntblk > 2048) cntblk = 2048;
  uint2* myst = staged2 + (size_t)j * 2048;
  for (int i = tid; i < cntblk; i += 1024)      // PRIVATE, fully coalesced flush
    myst[i] = lrec[i];
}

// K1: MERGED gather/sort + fp8-MFMA aggregation + GEMM. One block per 16-node
// bucket, 3125 blocks, 512 threads, ~31 KB LDS -> 4 blocks/CU.
// Phase A (round-9 verified): tab column, run scan, marker max-scan -> rid,
// one coalesced staged2 read/thread + key histogram, 32-padded per-wave CSR,
// scatter (pads stay {0,0} = zero-weight).
// Phase B ROUND-11: native mfma_f32_16x16x32_fp8_fp8 (round-10 lesson: the
// software fp8->bf16 decode was ~96 VALU ops/chunk = the biggest VALU block
// at 50% VALUBusy). Raw xq bytes ARE the B operand; A = key-selected fp8 w
// bytes; S-sum via 0x38(=1.0)-replicated ones operand. Bit-identical for
// this data: xq has no denormal bytes (f2fp8 flushes at encode), w=1 exact.
// A/B = 8 fp8 in i64, k=(lane>>4)*8+j (byte n = elem j=n); C/D layout is
// dtype-independent. Epilogue divide-by-S + full At write. Then 4-wave GEMM.
__global__ __launch_bounds__(512, 4) void aggemm_kernel(
    const unsigned short* __restrict__ tab,
    const uint2* __restrict__ staged2,
    const unsigned char* __restrict__ xq,
    const unsigned short* __restrict__ xb,
    const unsigned short* __restrict__ Bf2,
    const float* __restrict__ bsum,
    float* __restrict__ out) {
  __shared__ __align__(16) unsigned short At[16 * PITCH];  // 18.5 KB
  __shared__ short rid[512];                    // 1 KB
  __shared__ unsigned short tabcol[NBIN];       // 1 KB
  __shared__ short runbase[NBIN];               // 1 KB
  __shared__ uint2 sorted[BCAP2];               // 5.75 KB, padded CSR-by-key
  __shared__ int hist[512];                     // counts -> padded cursors
  __shared__ int scn[513];                      // unpadded key prefix
  __shared__ int wsum[8];
  __shared__ int wbase_s[8];                    // padded per-wave bases
  __shared__ int cnt_s;
  int tid = threadIdx.x;
  int lane = tid & 63;
  int wave = tid >> 6;
  // bijective chunked XCD swizzle: nwg=3125, q=390, r=5
  int orig = blockIdx.x;
  int xcd = orig & 7;
  int lid = orig >> 3;
  int b = ((xcd < 5) ? xcd * 391 : (5 * 391 + (xcd - 5) * 390)) + lid;
  int nodeBase = b * 16;

  // --- S1: init (incl. zero-fill padded sorted) + tab column + run scan ---
  hist[tid] = 0;
  rid[tid] = 0;
  sorted[tid] = make_uint2(0u, 0u);
  if (tid < BCAP2 - 512) sorted[512 + tid] = make_uint2(0u, 0u);
  unsigned tv = (tid < NBIN) ? (unsigned)tab[(size_t)tid * TPITCH + b] : 0u;
  int rc = (int)(tv >> 11);
  int inc = rc;
  #pragma unroll
  for (int dd = 1; dd < 64; dd <<= 1) {
    int tt = __shfl_up(inc, dd);
    if (lane >= dd) inc += tt;
  }
  if (lane == 63) wsum[wave] = inc;
  __syncthreads();
  // --- S2: cross-wave offset, store runbase/tabcol, markers ---
  {
    int off = 0;
    #pragma unroll
    for (int i = 0; i < 8; i++) { int pv = wsum[i]; off += (i < wave) ? pv : 0; }
    int excl = off + inc - rc;
    if (tid < NBIN) {
      tabcol[tid] = (unsigned short)tv;
      runbase[tid] = (short)excl;
      if (rc > 0 && excl < BCAP) rid[excl] = (short)tid;   // run marker
    }
    if (tid == 511) cnt_s = (off + inc < BCAP) ? (off + inc) : BCAP;
  }
  __syncthreads();
  // --- S3: 1-elem inclusive MAX-scan over rid[0..512) -> run id per record ---
  {
    int a0 = (int)rid[tid];
    int minc = a0;
    #pragma unroll
    for (int dd = 1; dd < 64; dd <<= 1) {
      int tt = __shfl_up(minc, dd);
      if (lane >= dd) minc = max(minc, tt);
    }
    if (lane == 63) wsum[wave] = minc;
    __syncthreads();
    int moff = 0;
    #pragma unroll
    for (int i = 0; i < 8; i++) { int pv = wsum[i]; moff = (i < wave) ? max(moff, pv) : moff; }
    int ew = __shfl_up(minc, 1);
    int p = (lane > 0) ? max(moff, ew) : moff;
    rid[tid] = (short)max(p, a0);
  }
  __syncthreads();
  // --- S5: ONE coalesced record read/thread + key histogram ---
  int cntC = cnt_s;
  uint2 g0 = make_uint2(0, 0);
  int k0 = -1;
  if (tid < cntC) {
    int jr = (int)rid[tid];
    int pp = (int)(tabcol[jr] & 0x7FFu) + tid - (int)runbase[jr];
    g0 = staged2[(size_t)jr * 2048 + pp];
    k0 = (int)(g0.x >> 23);                     // 7-bit key
    atomicAdd(&hist[k0], 1);
  }
  __syncthreads();
  // --- S6: 8-wave exclusive scan of key counts -> scn (unpadded) ---
  {
    int v = hist[tid];
    int kinc = v;
    #pragma unroll
    for (int dd = 1; dd < 64; dd <<= 1) {
      int tt = __shfl_up(kinc, dd);
      if (lane >= dd) kinc += tt;
    }
    if (lane == 63) wsum[wave] = kinc;
    __syncthreads();
    int off = 0;
    #pragma unroll
    for (int i = 0; i < 8; i++) { int pv = wsum[i]; off += (i < wave) ? pv : 0; }
    scn[tid] = off + kinc - v;
    if (tid == 511) scn[512] = off + kinc;
  }
  __syncthreads();
  // --- S7: padded per-wave bases (each wave's range rounded up to 32) ---
  if (wave == 0) {
    int Lw = (lane < 8) ? (scn[lane * 16 + 16] - scn[lane * 16]) : 0;
    int pw = (Lw + 31) & ~31;
    int inc2 = pw;
    #pragma unroll
    for (int dd = 1; dd < 8; dd <<= 1) {
      int tt = __shfl_up(inc2, dd);
      if (lane >= dd) inc2 += tt;
    }
    if (lane < 8) wbase_s[lane] = inc2 - pw;
  }
  __syncthreads();
  if (tid < 128) hist[tid] = wbase_s[tid >> 4] + scn[tid] - scn[tid & ~15];
  __syncthreads();
  // --- S8: scatter -> sorted[] (padded CSR by key; pads stay {0,0}) ---
  if (k0 >= 0) { int pq = atomicAdd(&hist[k0], 1); sorted[pq] = g0; }
  __syncthreads();

  // --- Phase B: fp8-MFMA aggregation. Wave w: keys 16w..16w+15, padded range.
  {
    int Lw = scn[wave * 16 + 16] - scn[wave * 16];
    int base0 = wbase_s[wave];
    int nch = (Lw + 31) >> 5;
    int fl = lane & 15;
    int q8 = (lane >> 4) * 8;
    unsigned mg = (unsigned)(wave * 16 + fl);   // my A-row = global key
    float4v acc0 = {0.f,0.f,0.f,0.f}, acc1 = {0.f,0.f,0.f,0.f};
    float4v acc2 = {0.f,0.f,0.f,0.f}, acc3 = {0.f,0.f,0.f,0.f};
    float4v accS = {0.f,0.f,0.f,0.f};
    const i64 onesA = 0x3838383838383838LL;     // 8x fp8 e4m3 1.0
    for (int c = 0; c < nch; c++) {
      int rb = base0 + c * 32 + q8;
      uint2 r0 = sorted[rb + 0], r1 = sorted[rb + 1], r2 = sorted[rb + 2], r3 = sorted[rb + 3];
      uint2 r4 = sorted[rb + 4], r5 = sorted[rb + 5], r6 = sorted[rb + 6], r7 = sorted[rb + 7];
      // A-frag: fp8 w byte if rec's key == my row else 0 (pads: y=0)
      unsigned s0 = ((r0.x >> 23) == mg) ? r0.y : 0u;
      unsigned s1 = ((r1.x >> 23) == mg) ? r1.y : 0u;
      unsigned s2 = ((r2.x >> 23) == mg) ? r2.y : 0u;
      unsigned s3 = ((r3.x >> 23) == mg) ? r3.y : 0u;
      unsigned s4 = ((r4.x >> 23) == mg) ? r4.y : 0u;
      unsigned s5 = ((r5.x >> 23) == mg) ? r5.y : 0u;
      unsigned s6 = ((r6.x >> 23) == mg) ? r6.y : 0u;
      unsigned s7 = ((r7.x >> 23) == mg) ? r7.y : 0u;
      i64 af = (i64)(unsigned)pk4(s0, s1, s2, s3) | ((i64)pk4(s4, s5, s6, s7) << 32);
      // B-frags: raw fp8 bytes X[rec][feat]; feat t*16+fl of recs q8..q8+7
      unsigned o0 = (r0.x & 0x3FFFC0u) + (unsigned)fl;
      unsigned o1 = (r1.x & 0x3FFFC0u) + (unsigned)fl;
      unsigned o2 = (r2.x & 0x3FFFC0u) + (unsigned)fl;
      unsigned o3 = (r3.x & 0x3FFFC0u) + (unsigned)fl;
      unsigned o4 = (r4.x & 0x3FFFC0u) + (unsigned)fl;
      unsigned o5 = (r5.x & 0x3FFFC0u) + (unsigned)fl;
      unsigned o6 = (r6.x & 0x3FFFC0u) + (unsigned)fl;
      unsigned o7 = (r7.x & 0x3FFFC0u) + (unsigned)fl;
      unsigned b00 = xq[o0],      b10 = xq[o1],      b20 = xq[o2],      b30 = xq[o3];
      unsigned b40 = xq[o4],      b50 = xq[o5],      b60 = xq[o6],      b70 = xq[o7];
      unsigned b01 = xq[o0 + 16], b11 = xq[o1 + 16], b21 = xq[o2 + 16], b31 = xq[o3 + 16];
      unsigned b41 = xq[o4 + 16], b51 = xq[o5 + 16], b61 = xq[o6 + 16], b71 = xq[o7 + 16];
      unsigned b02 = xq[o0 + 32], b12 = xq[o1 + 32], b22 = xq[o2 + 32], b32 = xq[o3 + 32];
      unsigned b42 = xq[o4 + 32], b52 = xq[o5 + 32], b62 = xq[o6 + 32], b72 = xq[o7 + 32];
      unsigned b03 = xq[o0 + 48], b13 = xq[o1 + 48], b23 = xq[o2 + 48], b33 = xq[o3 + 48];
      unsigned b43 = xq[o4 + 48], b53 = xq[o5 + 48], b63 = xq[o6 + 48], b73 = xq[o7 + 48];
      i64 B0 = (i64)(unsigned)pk4(b00, b10, b20, b30) | ((i64)pk4(b40, b50, b60, b70) << 32);
      i64 B1 = (i64)(unsigned)pk4(b01, b11, b21, b31) | ((i64)pk4(b41, b51, b61, b71) << 32);
      i64 B2 = (i64)(unsigned)pk4(b02, b12, b22, b32) | ((i64)pk4(b42, b52, b62, b72) << 32);
      i64 B3 = (i64)(unsigned)pk4(b03, b13, b23, b33) | ((i64)pk4(b43, b53, b63, b73) << 32);
      acc0 = __builtin_amdgcn_mfma_f32_16x16x32_fp8_fp8(af, B0, acc0, 0, 0, 0);
      acc1 = __builtin_amdgcn_mfma_f32_16x16x32_fp8_fp8(af, B1, acc1, 0, 0, 0);
      acc2 = __builtin_amdgcn_mfma_f32_16x16x32_fp8_fp8(af, B2, acc2, 0, 0, 0);
      acc3 = __builtin_amdgcn_mfma_f32_16x16x32_fp8_fp8(af, B3, acc3, 0, 0, 0);
      accS = __builtin_amdgcn_mfma_f32_16x16x32_fp8_fp8(af, onesA, accS, 0, 0, 0);
    }
    // Epilogue: divide by S, write At (covers ALL 16 keys; empty -> 0)
    int rowg = lane >> 4;
    #pragma unroll
    for (int reg = 0; reg < 4; reg++) {
      int lk = rowg * 4 + reg;                  // local key (C row)
      float S = accS[reg];
      float rd = (S != 0.f) ? (1.0f / S) : 0.f;
      int rowo = (wave * 2 + (lk >> 3)) * PITCH + (lk & 7) * 64 + fl;
      At[rowo +  0] = f2bf(acc0[reg] * rd);
      At[rowo + 16] = f2bf(acc1[reg] * rd);
      At[rowo + 32] = f2bf(acc2[reg] * rd);
      At[rowo + 48] = f2bf(acc3[reg] * rd);
    }
  }
  {                                             // self-loop rows (L2-warm)
    int node0 = nodeBase + wave * 2;            // <= 49998 (3125*16 exact)
    At[(wave * 2) * PITCH + 512 + lane]     = xb[(size_t)node0 * 64 + lane];
    At[(wave * 2 + 1) * PITCH + 512 + lane] = xb[(size_t)(node0 + 1) * 64 + lane];
  }
  __syncthreads();

  // --- GEMM: waves 0-3; wave = col tile (verified layout) ---
  if (wave < 4) {
    int m = lane & 15;
    int q = lane >> 4;
    float4v o4 = {0.f, 0.f, 0.f, 0.f};
    const short8* Bp = (const short8*)Bf2;
    #pragma unroll
    for (int ks = 0; ks < 18; ks++) {
      short8 a = *(const short8*)(At + m * PITCH + ks * 32 + q * 8);
      short8 bfr = Bp[(ks * 4 + wave) * 64 + lane];
      o4 = __builtin_amdgcn_mfma_f32_16x16x32_bf16(a, bfr, o4, 0, 0, 0);
    }
    int c = wave * 16 + m;
    float bias = bsum[c];
    #pragma unroll
    for (int rr2 = 0; rr2 < 4; rr2++) {
      out[(size_t)(nodeBase + q * 4 + rr2) * 64 + c] = fmaxf(o4[rr2] + bias, 0.0f);
    }
  }
}

extern "C" void kernel_launch(void* const* d_in, const int* in_sizes, int n_in,
                              void* d_out, int out_size, void* d_ws, size_t ws_size,
                              hipStream_t stream) {
  const float* x     = (const float*)d_in[0];
  const int*   esrc  = (const int*)d_in[1];
  const int*   edst  = (const int*)d_in[2];
  const int*   erel  = (const int*)d_in[3];
  const float* ew    = (const float*)d_in[4];
  const float* Wlin  = (const float*)d_in[5];
  const float* blin  = (const float*)d_in[6];
  const float* Wself = (const float*)d_in[7];
  const float* bself = (const float*)d_in[8];
  float* out = (float*)d_out;

  char* ws = (char*)d_ws;
  size_t off = 0;
  auto alloc = [&](size_t bytes) -> void* {
    void* p = ws + off;
    off += (bytes + 255) & ~(size_t)255;
    return p;
  };
  uint2*          staged2 = (uint2*)alloc((size_t)NBIN * 2048 * sizeof(uint2));                   // 8.0 MB
  unsigned short* tab     = (unsigned short*)alloc((size_t)NBIN * TPITCH * sizeof(unsigned short)); // 3.1 MB
  unsigned short* Bf2     = (unsigned short*)alloc((size_t)PREPN * sizeof(unsigned short));
  float*          bsum    = (float*)alloc(64 * sizeof(float));
  unsigned short* xb      = (unsigned short*)alloc((size_t)NNODES * DIM * sizeof(unsigned short)); // 6.4 MB
  unsigned char*  xq      = (unsigned char*)alloc((size_t)NNODES * DIM);                           // 3.2 MB

  const int E2 = NEDGES / 2;
  build_kernel<<<NBIN, 1024, 0, stream>>>((const float4*)x, Wlin, Wself, blin, bself,
                                          (const int2*)esrc, (const int2*)edst,
                                          (const int2*)erel, (const float2*)ew,
                                          (us4*)xb, (unsigned int*)xq, Bf2, bsum,
                                          staged2, tab, E2);
  aggemm_kernel<<<NBINB, 512, 0, stream>>>(tab, staged2, xq, xb, Bf2, bsum, out);
}

// Round 12
// 127.668 us; speedup vs baseline: 1.0625x; 1.0625x over previous
//
#include <hip/hip_runtime.h>
#include <stdint.h>

// Problem constants
#define NNODES 50000
#define NEDGES 1000000
#define DIM    64
#define NREL   8
#define NBIN   489          // build blocks: 2048 edges each (489*2048 >= 1M)
#define NBINB  3125         // 16-node bins (dst>>4); 3125*16 == 50000 exactly
#define NBINBP 4096         // lhist/lscan pad to 1024*4 for the 4-elem scan
#define TPITCH 3136         // tab row pitch (ushorts), row-major by build block
#define BCAP   480          // per-bucket record cap (mean 320, sd ~18 -> +8.9 sigma)
#define BCAP2  736          // padded sorted[] capacity: 480 + 8 groups * 31 pad
#define PITCH  584          // At row pitch (shorts); 584/2=292 dwords, 292%32=4 ->
                            // GEMM b128 reads are 2-way banked (free) vs 592's 4-way
#define PREPN  (18 * 4 * 64 * 8)

typedef __attribute__((ext_vector_type(8))) short short8;
typedef __attribute__((ext_vector_type(4))) float float4v;
typedef __attribute__((ext_vector_type(4))) unsigned short us4;
typedef long long i64;

__device__ __forceinline__ unsigned short f2bf(float f) {
  unsigned int u = __float_as_uint(f);
  unsigned int r = (u + 0x7FFF + ((u >> 16) & 1)) >> 16;   // round-nearest-even
  return (unsigned short)r;
}
// f32 -> fp8 e4m3 (RNE, tiny values flushed to sign-only; |x|<6 so no sat needed)
__device__ __forceinline__ unsigned int f2fp8(float f) {
  unsigned u = __float_as_uint(f);
  unsigned s = (u >> 24) & 0x80u;
  unsigned a = u & 0x7FFFFFFFu;
  if (a < 0x3C800000u) return s;                 // |x| < 2^-6
  unsigned r = a + 0x7FFFFu + ((a >> 20) & 1u);
  return s | (((r >> 20) - 960u) & 0x7Fu);
}
// pack 4 zero-extended bytes -> dword (byte n = fp8 element j=n)
__device__ __forceinline__ unsigned pk4(unsigned a, unsigned b, unsigned c, unsigned d) {
  return a | (b << 8) | (c << 16) | (d << 24);
}

// K0: build (UNCHANGED from round 11). 1024 threads/block, 2 edges/thread.
// Prologue: x f32 -> bf16 (xb) AND fp8 (xq) + B-prep + bias. Main: LDS
// counting sort by 16-node bin (dst>>4), flush to staged2[j*2048..].
// Record: x=(src<<6)|key<<23, key=(dst&15)*8+rel; y = f2fp8(w).
// tab[j*TPITCH+bin] = off(11b)|cnt(5b)<<11.
__global__ __launch_bounds__(1024, 8) void build_kernel(
    const float4* __restrict__ x4,
    const float* __restrict__ Wlin, const float* __restrict__ Wself,
    const float* __restrict__ blin, const float* __restrict__ bself,
    const int2* __restrict__ src2, const int2* __restrict__ dst2,
    const int2* __restrict__ rel2, const float2* __restrict__ w2,
    us4* __restrict__ xb, unsigned int* __restrict__ xq4,
    unsigned short* __restrict__ Bf2, float* __restrict__ bsum,
    uint2* __restrict__ staged2, unsigned short* __restrict__ tab, int E2) {
  __shared__ int lhist[NBINBP];             // 16 KB
  __shared__ int lscan[NBINBP];             // 16 KB
  __shared__ uint2 lrec[2048];              // 16 KB
  __shared__ int wsumB[16];
  int tid = threadIdx.x;
  int lane = tid & 63;
  int wave = tid >> 6;                      // 0..15
  int j = blockIdx.x;
  int gid = j * 1024 + tid;
  const int TOT = NBIN * 1024;

  for (int t = gid; t < NNODES * DIM / 4; t += TOT) {
    float4 v = x4[t];
    us4 o;
    o.x = f2bf(v.x); o.y = f2bf(v.y); o.z = f2bf(v.z); o.w = f2bf(v.w);
    xb[t] = o;
    xq4[t] = f2fp8(v.x) | (f2fp8(v.y) << 8) | (f2fp8(v.z) << 16) | (f2fp8(v.w) << 24);
  }
  if (gid < PREPN) {
    int t = gid;
    int jj = t & 7;
    int l  = (t >> 3) & 63;
    int ct = (t >> 9) & 3;
    int ks = t >> 11;
    int k = ks * 32 + (l >> 4) * 8 + jj;
    int c = ct * 16 + (l & 15);
    float v = (k < 512) ? Wlin[(size_t)k * 64 + c] : Wself[(size_t)(k - 512) * 64 + c];
    Bf2[t] = f2bf(v);
  }
  if (gid < 64) bsum[gid] = blin[gid] + bself[gid];

  for (int i = tid; i < NBINBP; i += 1024) lhist[i] = 0;
  __syncthreads();
  bool valid = gid < E2;
  int2 s = {0,0}, d = {0,0}, r = {0,0};
  float2 w = {0.f,0.f};
  if (valid) { s = src2[gid]; d = dst2[gid]; r = rel2[gid]; w = w2[gid]; }
  int b0=0,b1=0,p0=0,p1=0;
  if (valid) {
    b0 = d.x >> 4; p0 = atomicAdd(&lhist[b0], 1);
    b1 = d.y >> 4; p1 = atomicAdd(&lhist[b1], 1);
  }
  __syncthreads();
  {                 // 16-wave exclusive scan of 4096 bin counts, 4 elems/thread
    int base4 = tid * 4;
    int l0 = lhist[base4 + 0], l1 = lhist[base4 + 1],
        l2 = lhist[base4 + 2], l3 = lhist[base4 + 3];
    int c1 = l0, c2 = c1 + l1, c3 = c2 + l2, s4 = c3 + l3;
    int inc = s4;
    #pragma unroll
    for (int dd = 1; dd < 64; dd <<= 1) {
      int tt = __shfl_up(inc, dd);
      if (lane >= dd) inc += tt;
    }
    if (lane == 63) wsumB[wave] = inc;
    __syncthreads();
    int off = 0;
    #pragma unroll
    for (int i = 0; i < 16; i++) { int pv = wsumB[i]; off += (i < wave) ? pv : 0; }
    int excl = off + inc - s4;
    lscan[base4 + 0] = excl;
    lscan[base4 + 1] = excl + c1;
    lscan[base4 + 2] = excl + c2;
    lscan[base4 + 3] = excl + c3;
  }
  __syncthreads();
  if (valid) {
    int q;
    unsigned k0 = (((unsigned)(d.x & 15) << 3) | (unsigned)r.x) << 23;
    unsigned k1 = (((unsigned)(d.y & 15) << 3) | (unsigned)r.y) << 23;
    q = lscan[b0] + p0; lrec[q] = make_uint2(((unsigned)s.x << 6) | k0, f2fp8(w.x));
    q = lscan[b1] + p1; lrec[q] = make_uint2(((unsigned)s.y << 6) | k1, f2fp8(w.y));
  }
  __syncthreads();
  for (int i = tid; i < NBINB; i += 1024) {    // COALESCED row-major run table
    int c = lhist[i];
    int cc = (c < 31) ? c : 31;
    unsigned short pk = (c > 0) ? (unsigned short)((unsigned)lscan[i] | ((unsigned)cc << 11)) : (unsigned short)0;
    tab[(size_t)j * TPITCH + i] = pk;
  }
  int cntblk = NEDGES - j * 2048;
  if (cntblk > 2048) cntblk = 2048;
  uint2* myst = staged2 + (size_t)j * 2048;
  for (int i = tid; i < cntblk; i += 1024)      // PRIVATE, fully coalesced flush
    myst[i] = lrec[i];
}

// K1: MERGED gather/sort + fp8-MFMA aggregation + GEMM.
// ROUND-12 CHANGE: 256 threads/block (was 512). Round-11 lesson: occupancy
// stuck at 45% -- 512-thread blocks cap at 4/CU (wave limit), 8 barriers
// serialize all 8 waves, and waves 4-7 idle through the GEMM. 256-thread
// blocks: ~28.6 KB LDS -> 5 blocks/CU x 4 waves = 20 waves static, finer
// barrier scope, ALL waves do the GEMM. Same bucket size (16 nodes), same
// verified phase algebra: phase A = 2 records/thread + 2-elem scans; phase B
// per wave runs key-groups {w, w+4} sequentially. PITCH 592->584 (2-way
// banked GEMM reads instead of 4-way).
__global__ __launch_bounds__(256, 5) void aggemm_kernel(
    const unsigned short* __restrict__ tab,
    const uint2* __restrict__ staged2,
    const unsigned char* __restrict__ xq,
    const unsigned short* __restrict__ xb,
    const unsigned short* __restrict__ Bf2,
    const float* __restrict__ bsum,
    float* __restrict__ out) {
  __shared__ __align__(16) unsigned short At[16 * PITCH];  // 18.25 KB
  __shared__ short rid[512];                    // 1 KB
  __shared__ unsigned short tabcol[NBIN];       // 1 KB
  __shared__ short runbase[NBIN];               // 1 KB
  __shared__ uint2 sorted[BCAP2];               // 5.75 KB, padded CSR-by-key
  __shared__ int hist[128];                     // key counts -> padded cursors
  __shared__ int scn[129];                      // unpadded key prefix
  __shared__ int wsum[4];
  __shared__ int wsum2[2];
  __shared__ int wbase_s[8];                    // padded per-group bases
  __shared__ int cnt_s;
  int tid = threadIdx.x;                        // 0..255
  int lane = tid & 63;
  int wave = tid >> 6;                          // 0..3
  // bijective chunked XCD swizzle: nwg=3125, q=390, r=5
  int orig = blockIdx.x;
  int xcd = orig & 7;
  int lid = orig >> 3;
  int b = ((xcd < 5) ? xcd * 391 : (5 * 391 + (xcd - 5) * 390)) + lid;
  int nodeBase = b * 16;

  // --- S1: init + tab column (2 cols/thread) + run scan (2 elems/thread) ---
  if (tid < 128) hist[tid] = 0;
  rid[tid] = 0; rid[tid + 256] = 0;
  sorted[tid] = make_uint2(0u, 0u);
  sorted[tid + 256] = make_uint2(0u, 0u);
  if (tid < BCAP2 - 512) sorted[tid + 512] = make_uint2(0u, 0u);
  int i0 = 2 * tid, i1 = 2 * tid + 1;
  unsigned tv0 = (i0 < NBIN) ? (unsigned)tab[(size_t)i0 * TPITCH + b] : 0u;
  unsigned tv1 = (i1 < NBIN) ? (unsigned)tab[(size_t)i1 * TPITCH + b] : 0u;
  int rc0 = (int)(tv0 >> 11), rc1 = (int)(tv1 >> 11);
  {
    int s2 = rc0 + rc1;
    int inc = s2;
    #pragma unroll
    for (int dd = 1; dd < 64; dd <<= 1) {
      int tt = __shfl_up(inc, dd);
      if (lane >= dd) inc += tt;
    }
    if (lane == 63) wsum[wave] = inc;
    __syncthreads();
    int off = 0;
    #pragma unroll
    for (int i = 0; i < 4; i++) { int pv = wsum[i]; off += (i < wave) ? pv : 0; }
    int excl = off + inc - s2;
    if (i0 < NBIN) {
      tabcol[i0] = (unsigned short)tv0;
      runbase[i0] = (short)excl;
      if (rc0 > 0 && excl < BCAP) rid[excl] = (short)i0;   // run marker
    }
    int excl1 = excl + rc0;
    if (i1 < NBIN) {
      tabcol[i1] = (unsigned short)tv1;
      runbase[i1] = (short)excl1;
      if (rc1 > 0 && excl1 < BCAP) rid[excl1] = (short)i1;
    }
    if (tid == 255) cnt_s = (off + inc < BCAP) ? (off + inc) : BCAP;
  }
  __syncthreads();
  // --- S3: inclusive MAX-scan over rid[0..512), 2 elems/thread ---
  {
    int a0 = (int)rid[i0], a1 = (int)rid[i1];
    int m2 = max(a0, a1);
    int minc = m2;
    #pragma unroll
    for (int dd = 1; dd < 64; dd <<= 1) {
      int tt = __shfl_up(minc, dd);
      if (lane >= dd) minc = max(minc, tt);
    }
    if (lane == 63) wsum[wave] = minc;
    __syncthreads();
    int moff = 0;
    #pragma unroll
    for (int i = 0; i < 4; i++) { int pv = wsum[i]; moff = (i < wave) ? max(moff, pv) : moff; }
    int ew = __shfl_up(minc, 1);
    int p = (lane > 0) ? max(moff, ew) : moff;
    int r0 = max(p, a0);
    int r1 = max(r0, a1);
    rid[i0] = (short)r0; rid[i1] = (short)r1;
  }
  __syncthreads();
  // --- S5: 2 coalesced record reads/thread + key histogram ---
  int cntC = cnt_s;
  uint2 g0 = make_uint2(0, 0), g1 = make_uint2(0, 0);
  int k0 = -1, k1 = -1;
  {
    int t0 = tid, t1 = tid + 256;
    if (t0 < cntC) {
      int jr = (int)rid[t0];
      int pp = (int)(tabcol[jr] & 0x7FFu) + t0 - (int)runbase[jr];
      g0 = staged2[(size_t)jr * 2048 + pp];
      k0 = (int)(g0.x >> 23);
      atomicAdd(&hist[k0], 1);
    }
    if (t1 < cntC) {
      int jr = (int)rid[t1];
      int pp = (int)(tabcol[jr] & 0x7FFu) + t1 - (int)runbase[jr];
      g1 = staged2[(size_t)jr * 2048 + pp];
      k1 = (int)(g1.x >> 23);
      atomicAdd(&hist[k1], 1);
    }
  }
  __syncthreads();
  // --- S6: exclusive scan of 128 key counts (waves 0-1) ---
  {
    int v = (tid < 128) ? hist[tid] : 0;
    int kinc = v;
    #pragma unroll
    for (int dd = 1; dd < 64; dd <<= 1) {
      int tt = __shfl_up(kinc, dd);
      if (lane >= dd) kinc += tt;
    }
    if (lane == 63 && wave < 2) wsum2[wave] = kinc;
    __syncthreads();
    if (tid < 128) {
      int off = (wave == 1) ? wsum2[0] : 0;
      scn[tid] = off + kinc - v;
      if (tid == 127) scn[128] = off + kinc;
    }
  }
  __syncthreads();
  // --- S7: padded per-group bases (8 groups of 16 keys, each padded to 32) ---
  if (wave == 0) {
    int Lw = (lane < 8) ? (scn[lane * 16 + 16] - scn[lane * 16]) : 0;
    int pw = (Lw + 31) & ~31;
    int inc2 = pw;
    #pragma unroll
    for (int dd = 1; dd < 8; dd <<= 1) {
      int tt = __shfl_up(inc2, dd);
      if (lane >= dd) inc2 += tt;
    }
    if (lane < 8) wbase_s[lane] = inc2 - pw;
  }
  __syncthreads();
  if (tid < 128) hist[tid] = wbase_s[tid >> 4] + scn[tid] - scn[tid & ~15];
  __syncthreads();
  // --- S8: scatter -> sorted[] (padded CSR by key; pads stay {0,0}) ---
  if (k0 >= 0) { int pq = atomicAdd(&hist[k0], 1); sorted[pq] = g0; }
  if (k1 >= 0) { int pq = atomicAdd(&hist[k1], 1); sorted[pq] = g1; }
  __syncthreads();

  // --- Phase B: fp8-MFMA aggregation. Wave w handles key-groups w and w+4.
  {
    int fl = lane & 15;
    int q8 = (lane >> 4) * 8;
    const i64 onesA = 0x3838383838383838LL;     // 8x fp8 e4m3 1.0
    for (int g = wave; g < 8; g += 4) {
      int kbase = g * 16;
      int Lw = scn[kbase + 16] - scn[kbase];
      int base0 = wbase_s[g];
      int nch = (Lw + 31) >> 5;
      unsigned mg = (unsigned)(kbase + fl);     // my A-row = global key
      float4v acc0 = {0.f,0.f,0.f,0.f}, acc1 = {0.f,0.f,0.f,0.f};
      float4v acc2 = {0.f,0.f,0.f,0.f}, acc3 = {0.f,0.f,0.f,0.f};
      float4v accS = {0.f,0.f,0.f,0.f};
      for (int c = 0; c < nch; c++) {
        int rb = base0 + c * 32 + q8;
        uint2 r0 = sorted[rb + 0], r1 = sorted[rb + 1], r2 = sorted[rb + 2], r3 = sorted[rb + 3];
        uint2 r4 = sorted[rb + 4], r5 = sorted[rb + 5], r6 = sorted[rb + 6], r7 = sorted[rb + 7];
        unsigned s0 = ((r0.x >> 23) == mg) ? r0.y : 0u;
        unsigned s1 = ((r1.x >> 23) == mg) ? r1.y : 0u;
        unsigned s2 = ((r2.x >> 23) == mg) ? r2.y : 0u;
        unsigned s3 = ((r3.x >> 23) == mg) ? r3.y : 0u;
        unsigned s4 = ((r4.x >> 23) == mg) ? r4.y : 0u;
        unsigned s5 = ((r5.x >> 23) == mg) ? r5.y : 0u;
        unsigned s6 = ((r6.x >> 23) == mg) ? r6.y : 0u;
        unsigned s7 = ((r7.x >> 23) == mg) ? r7.y : 0u;
        i64 af = (i64)(unsigned)pk4(s0, s1, s2, s3) | ((i64)pk4(s4, s5, s6, s7) << 32);
        unsigned o0 = (r0.x & 0x3FFFC0u) + (unsigned)fl;
        unsigned o1 = (r1.x & 0x3FFFC0u) + (unsigned)fl;
        unsigned o2 = (r2.x & 0x3FFFC0u) + (unsigned)fl;
        unsigned o3 = (r3.x & 0x3FFFC0u) + (unsigned)fl;
        unsigned o4 = (r4.x & 0x3FFFC0u) + (unsigned)fl;
        unsigned o5 = (r5.x & 0x3FFFC0u) + (unsigned)fl;
        unsigned o6 = (r6.x & 0x3FFFC0u) + (unsigned)fl;
        unsigned o7 = (r7.x & 0x3FFFC0u) + (unsigned)fl;
        unsigned b00 = xq[o0],      b10 = xq[o1],      b20 = xq[o2],      b30 = xq[o3];
        unsigned b40 = xq[o4],      b50 = xq[o5],      b60 = xq[o6],      b70 = xq[o7];
        unsigned b01 = xq[o0 + 16], b11 = xq[o1 + 16], b21 = xq[o2 + 16], b31 = xq[o3 + 16];
        unsigned b41 = xq[o4 + 16], b51 = xq[o5 + 16], b61 = xq[o6 + 16], b71 = xq[o7 + 16];
        unsigned b02 = xq[o0 + 32], b12 = xq[o1 + 32], b22 = xq[o2 + 32], b32 = xq[o3 + 32];
        unsigned b42 = xq[o4 + 32], b52 = xq[o5 + 32], b62 = xq[o6 + 32], b72 = xq[o7 + 32];
        unsigned b03 = xq[o0 + 48], b13 = xq[o1 + 48], b23 = xq[o2 + 48], b33 = xq[o3 + 48];
        unsigned b43 = xq[o4 + 48], b53 = xq[o5 + 48], b63 = xq[o6 + 48], b73 = xq[o7 + 48];
        i64 B0 = (i64)(unsigned)pk4(b00, b10, b20, b30) | ((i64)pk4(b40, b50, b60, b70) << 32);
        i64 B1 = (i64)(unsigned)pk4(b01, b11, b21, b31) | ((i64)pk4(b41, b51, b61, b71) << 32);
        i64 B2 = (i64)(unsigned)pk4(b02, b12, b22, b32) | ((i64)pk4(b42, b52, b62, b72) << 32);
        i64 B3 = (i64)(unsigned)pk4(b03, b13, b23, b33) | ((i64)pk4(b43, b53, b63, b73) << 32);
        acc0 = __builtin_amdgcn_mfma_f32_16x16x32_fp8_fp8(af, B0, acc0, 0, 0, 0);
        acc1 = __builtin_amdgcn_mfma_f32_16x16x32_fp8_fp8(af, B1, acc1, 0, 0, 0);
        acc2 = __builtin_amdgcn_mfma_f32_16x16x32_fp8_fp8(af, B2, acc2, 0, 0, 0);
        acc3 = __builtin_amdgcn_mfma_f32_16x16x32_fp8_fp8(af, B3, acc3, 0, 0, 0);
        accS = __builtin_amdgcn_mfma_f32_16x16x32_fp8_fp8(af, onesA, accS, 0, 0, 0);
      }
      // Epilogue: divide by S, write At rows for this group (empty keys -> 0)
      int rowg = lane >> 4;
      #pragma unroll
      for (int reg = 0; reg < 4; reg++) {
        int lk = rowg * 4 + reg;                // local key (C row)
        float S = accS[reg];
        float rd = (S != 0.f) ? (1.0f / S) : 0.f;
        int rowo = (g * 2 + (lk >> 3)) * PITCH + (lk & 7) * 64 + fl;
        At[rowo +  0] = f2bf(acc0[reg] * rd);
        At[rowo + 16] = f2bf(acc1[reg] * rd);
        At[rowo + 32] = f2bf(acc2[reg] * rd);
        At[rowo + 48] = f2bf(acc3[reg] * rd);
      }
    }
  }
  {                                             // self-loop rows: 4 rows/wave
    int r0w = wave * 4;
    #pragma unroll
    for (int i = 0; i < 4; i++) {
      int node = nodeBase + r0w + i;            // < 50000 (3125*16 exact)
      At[(r0w + i) * PITCH + 512 + lane] = xb[(size_t)node * 64 + lane];
    }
  }
  __syncthreads();

  // --- GEMM: ALL 4 waves; wave = col tile (verified layout) ---
  {
    int m = lane & 15;
    int q = lane >> 4;
    float4v o4 = {0.f, 0.f, 0.f, 0.f};
    const short8* Bp = (const short8*)Bf2;
    #pragma unroll
    for (int ks = 0; ks < 18; ks++) {
      short8 a = *(const short8*)(At + m * PITCH + ks * 32 + q * 8);
      short8 bfr = Bp[(ks * 4 + wave) * 64 + lane];
      o4 = __builtin_amdgcn_mfma_f32_16x16x32_bf16(a, bfr, o4, 0, 0, 0);
    }
    int c = wave * 16 + m;
    float bias = bsum[c];
    #pragma unroll
    for (int rr2 = 0; rr2 < 4; rr2++) {
      out[(size_t)(nodeBase + q * 4 + rr2) * 64 + c] = fmaxf(o4[rr2] + bias, 0.0f);
    }
  }
}

extern "C" void kernel_launch(void* const* d_in, const int* in_sizes, int n_in,
                              void* d_out, int out_size, void* d_ws, size_t ws_size,
                              hipStream_t stream) {
  const float* x     = (const float*)d_in[0];
  const int*   esrc  = (const int*)d_in[1];
  const int*   edst  = (const int*)d_in[2];
  const int*   erel  = (const int*)d_in[3];
  const float* ew    = (const float*)d_in[4];
  const float* Wlin  = (const float*)d_in[5];
  const float* blin  = (const float*)d_in[6];
  const float* Wself = (const float*)d_in[7];
  const float* bself = (const float*)d_in[8];
  float* out = (float*)d_out;

  char* ws = (char*)d_ws;
  size_t off = 0;
  auto alloc = [&](size_t bytes) -> void* {
    void* p = ws + off;
    off += (bytes + 255) & ~(size_t)255;
    return p;
  };
  uint2*          staged2 = (uint2*)alloc((size_t)NBIN * 2048 * sizeof(uint2));                   // 8.0 MB
  unsigned short* tab     = (unsigned short*)alloc((size_t)NBIN * TPITCH * sizeof(unsigned short)); // 3.1 MB
  unsigned short* Bf2     = (unsigned short*)alloc((size_t)PREPN * sizeof(unsigned short));
  float*          bsum    = (float*)alloc(64 * sizeof(float));
  unsigned short* xb      = (unsigned short*)alloc((size_t)NNODES * DIM * sizeof(unsigned short)); // 6.4 MB
  unsigned char*  xq      = (unsigned char*)alloc((size_t)NNODES * DIM);                           // 3.2 MB

  const int E2 = NEDGES / 2;
  build_kernel<<<NBIN, 1024, 0, stream>>>((const float4*)x, Wlin, Wself, blin, bself,
                                          (const int2*)esrc, (const int2*)edst,
                                          (const int2*)erel, (const float2*)ew,
                                          (us4*)xb, (unsigned int*)xq, Bf2, bsum,
                                          staged2, tab, E2);
  aggemm_kernel<<<NBINB, 256, 0, stream>>>(tab, staged2, xq, xb, Bf2, bsum, out);
}